// Round 1
// baseline (643.250 us; speedup 1.0000x reference)
//
#include <hip/hip_runtime.h>
#include <cstdint>
#include <cstddef>

#define BN_   4
#define CC    96
#define C2    192
#define NN    3136
#define KNN   9
#define TILE  64
#define PT    8
#define NEG_BIG (-1.0e30f)

// ---------------------------------------------------------------------------
// top-9 list kept unordered; (mnv, mni, mns) caches the worst entry under the
// ordering (value desc, index asc) == jax.lax.top_k stable tie-break.
// Reject path = 1 compare. Accept path (rare) = replace + rescan of 9.
// ---------------------------------------------------------------------------
__device__ __forceinline__ void topk_insert(float v, int idx,
                                            float (&bv)[KNN], int (&bi)[KNN],
                                            float& mnv, int& mni, int& mns) {
  if (v > mnv || (v == mnv && idx < mni)) {
    #pragma unroll
    for (int j = 0; j < KNN; ++j) if (j == mns) { bv[j] = v; bi[j] = idx; }
    mnv = bv[0]; mni = bi[0]; mns = 0;
    #pragma unroll
    for (int j = 1; j < KNN; ++j) {
      bool worse = (bv[j] < mnv) || (bv[j] == mnv && bi[j] > mni);
      if (worse) { mnv = bv[j]; mni = bi[j]; mns = j; }
    }
  }
}

// ---------------------------------------------------------------------------
// K1: y1t[b][n][o] = bn1(fc1_w @ x + fc1_b).  n-major output for gathers.
// ---------------------------------------------------------------------------
__global__ __launch_bounds__(256) void k_fc1(const float* __restrict__ x,
                                             const float* __restrict__ w,
                                             const float* __restrict__ bias,
                                             const float* __restrict__ bn,
                                             float* __restrict__ y1t) {
  __shared__ float xs[CC * 64];  // [c][64]
  const int b = blockIdx.y, n0 = blockIdx.x * 64;
  const int t = threadIdx.x;
  for (int i = t; i < CC * 64; i += 256) {
    int c = i >> 6, nn = i & 63;
    xs[i] = x[((size_t)b * CC + c) * NN + n0 + nn];
  }
  __syncthreads();
  const int nn = t & 63;
  const int og = __builtin_amdgcn_readfirstlane(t >> 6);  // wave-uniform -> s_load weights
  float acc[24];
  #pragma unroll
  for (int i = 0; i < 24; ++i) acc[i] = 0.f;
  for (int c = 0; c < CC; ++c) {
    float xv = xs[c * 64 + nn];                 // bank = nn%32, 2-way: free
    const float* wp = w + (size_t)(og * 24) * CC + c;
    #pragma unroll
    for (int oi = 0; oi < 24; ++oi) acc[oi] = fmaf(wp[oi * CC], xv, acc[oi]);
  }
  #pragma unroll
  for (int oi = 0; oi < 24; ++oi) {
    int o = og * 24 + oi;
    float g = bn[o], be = bn[CC + o], mn = bn[2 * CC + o], vr = bn[3 * CC + o];
    float inv = g / sqrtf(vr + 1e-5f);
    float v = fmaf(acc[oi] + bias[o], inv, be - mn * inv);
    y1t[((size_t)b * NN + n0 + nn) * CC + o] = v;
  }
}

// ---------------------------------------------------------------------------
// K2: per-position L2 norm over channels; write xn (c-major) and sq.
// ---------------------------------------------------------------------------
__global__ __launch_bounds__(256) void k_norm(const float* __restrict__ y1t,
                                              float* __restrict__ xn,
                                              float* __restrict__ sq) {
  const int p = blockIdx.x * 256 + threadIdx.x;  // 49*256 == 12544 exactly
  const int b = p / NN, n = p % NN;
  const float* row = y1t + (size_t)p * CC;
  float s = 0.f;
  for (int c = 0; c < CC; c += 4) {
    float4 v = *(const float4*)(row + c);
    s += v.x * v.x; s += v.y * v.y; s += v.z * v.z; s += v.w * v.w;
  }
  float inv = 1.f / fmaxf(sqrtf(s), 1e-12f);
  float sqs = 0.f;
  for (int c = 0; c < CC; c += 4) {
    float4 v = *(const float4*)(row + c);
    v.x *= inv; v.y *= inv; v.z *= inv; v.w *= inv;
    xn[((size_t)b * CC + c + 0) * NN + n] = v.x;
    xn[((size_t)b * CC + c + 1) * NN + n] = v.y;
    xn[((size_t)b * CC + c + 2) * NN + n] = v.z;
    xn[((size_t)b * CC + c + 3) * NN + n] = v.w;
    sqs += v.x * v.x; sqs += v.y * v.y; sqs += v.z * v.z; sqs += v.w * v.w;
  }
  sq[p] = sqs;
}

// ---------------------------------------------------------------------------
// K3: fused Gram GEMM (64x64 fp32 tiles) + streaming top-9 per row.
// Column range split into 4 chunks (blockIdx.y) for grid parallelism.
// ---------------------------------------------------------------------------
__global__ __launch_bounds__(256) void k_dist(const float* __restrict__ xn,
                                              const float* __restrict__ sq,
                                              float* __restrict__ cand_v,
                                              int* __restrict__ cand_i) {
  __shared__ float As[CC * TILE];     // [kk][ri]
  __shared__ float Bs[CC * TILE];     // [kk][mi]
  __shared__ float Cs[TILE * 65];     // +1 pad: selection reads row-major, bank=row%32
  __shared__ float sqm[TILE];
  __shared__ float srow[TILE];
  const int rt = blockIdx.x, chunk = blockIdx.y, b = blockIdx.z;
  const int r0 = rt * TILE;
  const int t = threadIdx.x;
  const int mt0 = (49 * chunk) / 4, mt1 = (49 * (chunk + 1)) / 4;

  for (int i = t; i < CC * TILE; i += 256) {
    int c = i >> 6, ri = i & 63;
    As[i] = xn[((size_t)b * CC + c) * NN + r0 + ri];
  }
  if (t < TILE) srow[t] = sq[b * NN + r0 + t];

  float bv[KNN]; int bi[KNN];
  #pragma unroll
  for (int j = 0; j < KNN; ++j) { bv[j] = NEG_BIG; bi[j] = 0x7fffffff; }
  float mnv = NEG_BIG; int mni = 0x7fffffff; int mns = 0;

  const int row = t & 63, q = t >> 6;   // selection mapping (persists across tiles)
  const int ty = t >> 4, tx = t & 15;   // gemm mapping

  for (int mt = mt0; mt < mt1; ++mt) {
    const int m0 = mt * TILE;
    __syncthreads();  // prior selection done before Bs overwrite
    for (int i = t; i < CC * TILE; i += 256) {
      int c = i >> 6, mi = i & 63;
      Bs[i] = xn[((size_t)b * CC + c) * NN + m0 + mi];
    }
    if (t < TILE) sqm[t] = sq[b * NN + m0 + t];
    __syncthreads();

    float acc[4][4];
    #pragma unroll
    for (int i = 0; i < 4; ++i) { acc[i][0] = 0; acc[i][1] = 0; acc[i][2] = 0; acc[i][3] = 0; }
    #pragma unroll 4
    for (int kk = 0; kk < CC; ++kk) {
      float4 a = *(const float4*)&As[kk * 64 + ty * 4];
      float4 bb = *(const float4*)&Bs[kk * 64 + tx * 4];
      float av[4] = {a.x, a.y, a.z, a.w};
      float bw[4] = {bb.x, bb.y, bb.z, bb.w};
      #pragma unroll
      for (int i = 0; i < 4; ++i)
        #pragma unroll
        for (int j = 0; j < 4; ++j) acc[i][j] = fmaf(av[i], bw[j], acc[i][j]);
    }
    #pragma unroll
    for (int i = 0; i < 4; ++i)
      #pragma unroll
      for (int j = 0; j < 4; ++j)
        Cs[(ty * 4 + i) * 65 + tx * 4 + j] = acc[i][j];
    __syncthreads();

    float sr = srow[row];
    #pragma unroll
    for (int s2 = 0; s2 < 16; ++s2) {
      int mc = q * 16 + s2;
      float v = 2.f * Cs[row * 65 + mc] - sr - sqm[mc];
      topk_insert(v, m0 + mc, bv, bi, mnv, mni, mns);
    }
  }
  __syncthreads();

  // merge the 4 per-quarter lists of each row (reuse As as scratch)
  float* mvbuf = As;
  int* mibuf = (int*)(As + TILE * 4 * KNN);
  #pragma unroll
  for (int j = 0; j < KNN; ++j) {
    mvbuf[(row * 4 + q) * KNN + j] = bv[j];
    mibuf[(row * 4 + q) * KNN + j] = bi[j];
  }
  __syncthreads();
  if (t < TILE) {
    float fv[KNN]; int fi[KNN];
    #pragma unroll
    for (int j = 0; j < KNN; ++j) { fv[j] = NEG_BIG; fi[j] = 0x7fffffff; }
    float m2v = NEG_BIG; int m2i = 0x7fffffff; int m2s = 0;
    for (int qq = 0; qq < 4; ++qq)
      #pragma unroll
      for (int j = 0; j < KNN; ++j)
        topk_insert(mvbuf[(t * 4 + qq) * KNN + j], mibuf[(t * 4 + qq) * KNN + j],
                    fv, fi, m2v, m2i, m2s);
    size_t base = (((size_t)b * 4 + chunk) * NN + r0 + t) * KNN;
    #pragma unroll
    for (int j = 0; j < KNN; ++j) { cand_v[base + j] = fv[j]; cand_i[base + j] = fi[j]; }
  }
}

// ---------------------------------------------------------------------------
// K4: merge 4 chunk lists -> nn_idx (set of top-9; order irrelevant post-max).
// ---------------------------------------------------------------------------
__global__ __launch_bounds__(256) void k_nnmerge(const float* __restrict__ cand_v,
                                                 const int* __restrict__ cand_i,
                                                 int* __restrict__ nn_idx) {
  const int p = blockIdx.x * 256 + threadIdx.x;
  const int b = p / NN, n = p % NN;
  float fv[KNN]; int fi[KNN];
  #pragma unroll
  for (int j = 0; j < KNN; ++j) { fv[j] = NEG_BIG; fi[j] = 0x7fffffff; }
  float mnv = NEG_BIG; int mni = 0x7fffffff; int mns = 0;
  for (int ch = 0; ch < 4; ++ch) {
    size_t base = (((size_t)b * 4 + ch) * NN + n) * KNN;
    #pragma unroll
    for (int j = 0; j < KNN; ++j)
      topk_insert(cand_v[base + j], cand_i[base + j], fv, fi, mnv, mni, mns);
  }
  #pragma unroll
  for (int j = 0; j < KNN; ++j) nn_idx[(size_t)p * KNN + j] = fi[j];
}

// ---------------------------------------------------------------------------
// K5: gather + grouped conv + bias + bn + relu + max over K.
// Key algebraic saving: feat channels 0..95 are x_i (k-independent), so
// output channels 0..95 are k-independent -> computed once, no k loop.
// 8 positions/block; feat staged k-minor (stride 12) in LDS.
// ---------------------------------------------------------------------------
__global__ __launch_bounds__(256) void k_gconv(const float* __restrict__ y1t,
                                               const int* __restrict__ nn_idx,
                                               const float* __restrict__ gw,
                                               const float* __restrict__ gb,
                                               const float* __restrict__ bng,
                                               float* __restrict__ ymax) {
  __shared__ float wl[C2 * 49];        // stride 49 -> bank 17*oc%32, conflict-free
  __shared__ float xi[PT * CC];
  __shared__ float fj[PT * CC * 12];   // [p][c][k(pad 12)] : 48B rows, b128-aligned
  __shared__ int idxl[PT * KNN];
  const int t = threadIdx.x;
  const int p0 = blockIdx.x * PT;      // NN%PT==0 -> block never straddles batch
  const int b0 = p0 / NN;

  for (int i = t; i < C2 * 48; i += 256) wl[(i / 48) * 49 + (i % 48)] = gw[i];
  if (t < PT * KNN) idxl[t] = nn_idx[(size_t)p0 * KNN + t];
  for (int i = t; i < PT * CC; i += 256) xi[i] = y1t[(size_t)p0 * CC + i];
  __syncthreads();

  for (int i = t; i < PT * KNN * CC; i += 256) {
    int pk = i / CC, c = i % CC;
    int p = pk / KNN, k = pk % KNN;
    int j = idxl[p * KNN + k];
    float v = y1t[((size_t)b0 * NN + j) * CC + c] - xi[p * CC + c];
    fj[(p * CC + c) * 12 + k] = v;
  }
  __syncthreads();

  const int p = t >> 5, l = t & 31;
  const size_t pg = p0 + p;
  float* orow = ymax + pg * C2;
  const float* xip = xi + p * CC;
  const float* fp = fj + (size_t)p * CC * 12;

  auto bnrelu = [&](int oc, float a) -> float {
    float g = bng[oc], be = bng[C2 + oc], mn = bng[2 * C2 + oc], vr = bng[3 * C2 + oc];
    float inv = g / sqrtf(vr + 1e-5f);
    return fmaxf(fmaf(a + gb[oc], inv, be - mn * inv), 0.f);
  };

  {  // k-free half: oc = l, l+32, l+64
    const int oc0 = l, oc1 = l + 32, oc2 = l + 64;
    const int cb0 = (oc0 / 48) * 48, cb1 = (oc1 / 48) * 48, cb2 = (oc2 / 48) * 48;
    float a0 = 0.f, a1 = 0.f, a2 = 0.f;
    #pragma unroll 8
    for (int c = 0; c < 48; ++c) {
      a0 = fmaf(wl[oc0 * 49 + c], xip[cb0 + c], a0);
      a1 = fmaf(wl[oc1 * 49 + c], xip[cb1 + c], a1);
      a2 = fmaf(wl[oc2 * 49 + c], xip[cb2 + c], a2);
    }
    orow[oc0] = bnrelu(oc0, a0);
    orow[oc1] = bnrelu(oc1, a1);
    orow[oc2] = bnrelu(oc2, a2);
  }
  {  // k-dependent half: oc = 96+l, 128+l, 160+l; 27 accumulators
    const int oc0 = 96 + l, oc1 = 128 + l, oc2 = 160 + l;
    const int db0 = ((oc0 - 96) / 48) * 48, db1 = ((oc1 - 96) / 48) * 48,
              db2 = ((oc2 - 96) / 48) * 48;
    float acc0[KNN], acc1[KNN], acc2[KNN];
    #pragma unroll
    for (int k = 0; k < KNN; ++k) { acc0[k] = 0.f; acc1[k] = 0.f; acc2[k] = 0.f; }
    #pragma unroll 2
    for (int c = 0; c < 48; ++c) {
      float w0 = wl[oc0 * 49 + c], w1 = wl[oc1 * 49 + c], w2 = wl[oc2 * 49 + c];
      const float* f0 = fp + (db0 + c) * 12;
      const float* f1 = fp + (db1 + c) * 12;
      const float* f2 = fp + (db2 + c) * 12;
      #pragma unroll
      for (int k = 0; k < KNN; ++k) {
        acc0[k] = fmaf(w0, f0[k], acc0[k]);
        acc1[k] = fmaf(w1, f1[k], acc1[k]);
        acc2[k] = fmaf(w2, f2[k], acc2[k]);
      }
    }
    {
      float g = bng[oc0], be = bng[C2 + oc0], mn = bng[2 * C2 + oc0], vr = bng[3 * C2 + oc0];
      float inv = g / sqrtf(vr + 1e-5f), sh = be - mn * inv, bs = gb[oc0], m = 0.f;
      #pragma unroll
      for (int k = 0; k < KNN; ++k) m = fmaxf(m, fmaxf(fmaf(acc0[k] + bs, inv, sh), 0.f));
      orow[oc0] = m;
    }
    {
      float g = bng[oc1], be = bng[C2 + oc1], mn = bng[2 * C2 + oc1], vr = bng[3 * C2 + oc1];
      float inv = g / sqrtf(vr + 1e-5f), sh = be - mn * inv, bs = gb[oc1], m = 0.f;
      #pragma unroll
      for (int k = 0; k < KNN; ++k) m = fmaxf(m, fmaxf(fmaf(acc1[k] + bs, inv, sh), 0.f));
      orow[oc1] = m;
    }
    {
      float g = bng[oc2], be = bng[C2 + oc2], mn = bng[2 * C2 + oc2], vr = bng[3 * C2 + oc2];
      float inv = g / sqrtf(vr + 1e-5f), sh = be - mn * inv, bs = gb[oc2], m = 0.f;
      #pragma unroll
      for (int k = 0; k < KNN; ++k) m = fmaxf(m, fmaxf(fmaf(acc2[k] + bs, inv, sh), 0.f));
      orow[oc2] = m;
    }
  }
}

// ---------------------------------------------------------------------------
// K6: out = bn2(fc2_w @ ymax + fc2_b) + x
// ---------------------------------------------------------------------------
__global__ __launch_bounds__(256) void k_fc2(const float* __restrict__ ymax,
                                             const float* __restrict__ w2,
                                             const float* __restrict__ b2,
                                             const float* __restrict__ bn2,
                                             const float* __restrict__ xin,
                                             float* __restrict__ out) {
  __shared__ float ys[64 * 193];  // stride 193 -> bank (nn+c2)%32, conflict-free
  const int b = blockIdx.y, n0 = blockIdx.x * 64, t = threadIdx.x;
  for (int i = t; i < 64 * C2; i += 256) {
    int nn = i / C2, c2 = i % C2;
    ys[nn * 193 + c2] = ymax[((size_t)b * NN + n0 + nn) * C2 + c2];
  }
  __syncthreads();
  const int nn = t & 63;
  const int og = __builtin_amdgcn_readfirstlane(t >> 6);
  float acc[24];
  #pragma unroll
  for (int i = 0; i < 24; ++i) acc[i] = 0.f;
  const float* yrow = ys + nn * 193;
  for (int c2 = 0; c2 < C2; ++c2) {
    float yv = yrow[c2];
    const float* wp = w2 + (size_t)(og * 24) * C2 + c2;
    #pragma unroll
    for (int oi = 0; oi < 24; ++oi) acc[oi] = fmaf(wp[oi * C2], yv, acc[oi]);
  }
  #pragma unroll
  for (int oi = 0; oi < 24; ++oi) {
    int o = og * 24 + oi;
    float g = bn2[o], be = bn2[CC + o], mn = bn2[2 * CC + o], vr = bn2[3 * CC + o];
    float inv = g / sqrtf(vr + 1e-5f);
    float v = fmaf(acc[oi] + b2[o], inv, be - mn * inv);
    size_t off = ((size_t)b * CC + o) * NN + n0 + nn;
    out[off] = v + xin[off];
  }
}

// ---------------------------------------------------------------------------
extern "C" void kernel_launch(void* const* d_in, const int* in_sizes, int n_in,
                              void* d_out, int out_size, void* d_ws, size_t ws_size,
                              hipStream_t stream) {
  const float* x     = (const float*)d_in[0];
  const float* fc1_w = (const float*)d_in[1];
  const float* fc1_b = (const float*)d_in[2];
  const float* bn1   = (const float*)d_in[3];
  const float* gc_w  = (const float*)d_in[4];
  const float* gc_b  = (const float*)d_in[5];
  const float* bng   = (const float*)d_in[6];
  const float* fc2_w = (const float*)d_in[7];
  const float* fc2_b = (const float*)d_in[8];
  const float* bn2   = (const float*)d_in[9];
  float* out = (float*)d_out;

  float* ws = (float*)d_ws;
  float* y1t    = ws;                                    // B*N*C
  float* xn     = y1t + (size_t)BN_ * NN * CC;           // B*C*N
  float* sq     = xn + (size_t)BN_ * NN * CC;            // B*N
  float* ymax   = sq + (size_t)BN_ * NN;                 // B*N*C2
  float* cand_v = ymax + (size_t)BN_ * NN * C2;          // B*4*N*9
  int*   cand_i = (int*)(cand_v + (size_t)BN_ * 4 * NN * KNN);
  int*   nnidx  = (int*)(cand_i + (size_t)BN_ * 4 * NN * KNN);

  k_fc1<<<dim3(NN / 64, BN_), 256, 0, stream>>>(x, fc1_w, fc1_b, bn1, y1t);
  k_norm<<<dim3((BN_ * NN) / 256), 256, 0, stream>>>(y1t, xn, sq);
  k_dist<<<dim3(NN / TILE, 4, BN_), 256, 0, stream>>>(xn, sq, cand_v, cand_i);
  k_nnmerge<<<dim3((BN_ * NN) / 256), 256, 0, stream>>>(cand_v, cand_i, nnidx);
  k_gconv<<<dim3((BN_ * NN) / PT), 256, 0, stream>>>(y1t, nnidx, gc_w, gc_b, bng, ymax);
  k_fc2<<<dim3(NN / 64, BN_), 256, 0, stream>>>(ymax, fc2_w, fc2_b, bn2, x, out);
}

// Round 3
// 550.651 us; speedup vs baseline: 1.1682x; 1.1682x over previous
//
#include <hip/hip_runtime.h>
#include <cstdint>
#include <cstddef>

#define BN_   4
#define CC    96
#define C2    192
#define NN    3136
#define KNN   9
#define TILE  64
#define PT    8
#define NEG_BIG (-1.0e30f)

typedef __attribute__((ext_vector_type(8))) __bf16 bf16x8;
typedef __attribute__((ext_vector_type(4))) float f32x4;

__device__ __forceinline__ unsigned short f2bf(float f) {
  unsigned int u = __float_as_uint(f);
  unsigned int r = u + 0x7fffu + ((u >> 16) & 1u);   // RNE
  return (unsigned short)(r >> 16);
}
__device__ __forceinline__ float bf2f(unsigned short h) {
  return __uint_as_float(((unsigned int)h) << 16);
}

// ---------------------------------------------------------------------------
// top-9 list kept unordered; (mnv, mni, mns) caches the worst entry under the
// ordering (value desc, index asc) == jax.lax.top_k stable tie-break.
// ---------------------------------------------------------------------------
__device__ __forceinline__ void topk_insert(float v, int idx,
                                            float (&bv)[KNN], int (&bi)[KNN],
                                            float& mnv, int& mni, int& mns) {
  if (v > mnv || (v == mnv && idx < mni)) {
    #pragma unroll
    for (int j = 0; j < KNN; ++j) if (j == mns) { bv[j] = v; bi[j] = idx; }
    mnv = bv[0]; mni = bi[0]; mns = 0;
    #pragma unroll
    for (int j = 1; j < KNN; ++j) {
      bool worse = (bv[j] < mnv) || (bv[j] == mnv && bi[j] > mni);
      if (worse) { mnv = bv[j]; mni = bi[j]; mns = j; }
    }
  }
}

// ---------------------------------------------------------------------------
// K1: y1t[b][n][o] = bn1(fc1_w @ x + fc1_b).  n-major output for gathers.
// ---------------------------------------------------------------------------
__global__ __launch_bounds__(256) void k_fc1(const float* __restrict__ x,
                                             const float* __restrict__ w,
                                             const float* __restrict__ bias,
                                             const float* __restrict__ bn,
                                             float* __restrict__ y1t) {
  __shared__ float xs[CC * 64];  // [c][64]
  const int b = blockIdx.y, n0 = blockIdx.x * 64;
  const int t = threadIdx.x;
  for (int i = t; i < CC * 64; i += 256) {
    int c = i >> 6, nn = i & 63;
    xs[i] = x[((size_t)b * CC + c) * NN + n0 + nn];
  }
  __syncthreads();
  const int nn = t & 63;
  const int og = __builtin_amdgcn_readfirstlane(t >> 6);
  float acc[24];
  #pragma unroll
  for (int i = 0; i < 24; ++i) acc[i] = 0.f;
  for (int c = 0; c < CC; ++c) {
    float xv = xs[c * 64 + nn];
    const float* wp = w + (size_t)(og * 24) * CC + c;
    #pragma unroll
    for (int oi = 0; oi < 24; ++oi) acc[oi] = fmaf(wp[oi * CC], xv, acc[oi]);
  }
  #pragma unroll
  for (int oi = 0; oi < 24; ++oi) {
    int o = og * 24 + oi;
    float g = bn[o], be = bn[CC + o], mn = bn[2 * CC + o], vr = bn[3 * CC + o];
    float inv = g / sqrtf(vr + 1e-5f);
    float v = fmaf(acc[oi] + bias[o], inv, be - mn * inv);
    y1t[((size_t)b * NN + n0 + nn) * CC + o] = v;
  }
}

// ---------------------------------------------------------------------------
// K2: per-position L2 norm; emit bf16 split (hi, lo) of xn + sq.
// ---------------------------------------------------------------------------
__global__ __launch_bounds__(256) void k_norm(const float* __restrict__ y1t,
                                              unsigned short* __restrict__ xh,
                                              unsigned short* __restrict__ xl,
                                              float* __restrict__ sq) {
  const int p = blockIdx.x * 256 + threadIdx.x;  // 49*256 == 12544 exactly
  const float* row = y1t + (size_t)p * CC;
  float s = 0.f;
  for (int c = 0; c < CC; c += 4) {
    float4 v = *(const float4*)(row + c);
    s += v.x * v.x; s += v.y * v.y; s += v.z * v.z; s += v.w * v.w;
  }
  float inv = 1.f / fmaxf(sqrtf(s), 1e-12f);
  float sqs = 0.f;
  unsigned short* hrow = xh + (size_t)p * CC;
  unsigned short* lrow = xl + (size_t)p * CC;
  for (int c = 0; c < CC; ++c) {
    float v = row[c] * inv;
    sqs += v * v;
    unsigned short h = f2bf(v);
    float lo = v - bf2f(h);
    hrow[c] = h;
    lrow[c] = f2bf(lo);
  }
  sq[p] = sqs;
}

// ---------------------------------------------------------------------------
// K3: Gram via bf16-split MFMA (hh + hl + lh), fused streaming top-9.
// LDS: A-region (hi|lo) is dead after A-fragment register loads; Cs and the
// end-merge scratch alias it.  Total static LDS = 53.8 KB (< 64 KiB).
// ---------------------------------------------------------------------------
__global__ __launch_bounds__(256) void k_dist(const unsigned short* __restrict__ xh,
                                              const unsigned short* __restrict__ xl,
                                              const float* __restrict__ sq,
                                              float* __restrict__ cand_v,
                                              int* __restrict__ cand_i) {
  // row stride 104 ushorts = 208 B (multiple of 16) -> all b128 ops aligned
  __shared__ __align__(16) unsigned short sA[2 * 64 * 104];  // 26624 B
  __shared__ __align__(16) unsigned short sB[2 * 64 * 104];  // 26624 B
  __shared__ float sqm[TILE];
  __shared__ float srow[TILE];
  unsigned short* AsH = sA;
  unsigned short* AsL = sA + 64 * 104;
  unsigned short* BsH = sB;
  unsigned short* BsL = sB + 64 * 104;
  float* Cs = (float*)sA;                 // 64*65*4 = 16640 B, alias of dead A

  const int rt = blockIdx.x, chunk = blockIdx.y, b = blockIdx.z;
  const int r0 = rt * TILE;
  const int t = threadIdx.x;
  const int lane = t & 63, w = t >> 6;
  const int m16 = lane & 15, quad = lane >> 4;
  const int mt0 = (49 * chunk) / 4, mt1 = (49 * (chunk + 1)) / 4;

  for (int i = t; i < 64 * 12; i += 256) {
    int r = i / 12, ch = i % 12;
    const uint4* sH = (const uint4*)(xh + ((size_t)b * NN + r0 + r) * CC);
    const uint4* sL = (const uint4*)(xl + ((size_t)b * NN + r0 + r) * CC);
    *(uint4*)&AsH[r * 104 + ch * 8] = sH[ch];
    *(uint4*)&AsL[r * 104 + ch * 8] = sL[ch];
  }
  if (t < TILE) srow[t] = sq[b * NN + r0 + t];
  __syncthreads();

  // A fragments: lane holds A[m = lane&15][k = quad*8 + j], rows w*16+m
  bf16x8 ah[3], al[3];
  {
    const int arow = (w * 16 + m16) * 104 + quad * 8;
    #pragma unroll
    for (int kc = 0; kc < 3; ++kc) {
      ah[kc] = *(const bf16x8*)&AsH[arow + kc * 32];
      al[kc] = *(const bf16x8*)&AsL[arow + kc * 32];
    }
  }

  float bv[KNN]; int bi[KNN];
  #pragma unroll
  for (int j = 0; j < KNN; ++j) { bv[j] = NEG_BIG; bi[j] = 0x7fffffff; }
  float mnv = NEG_BIG; int mni = 0x7fffffff; int mns = 0;

  const int row = t & 63, q = t >> 6;   // selection mapping

  for (int mt = mt0; mt < mt1; ++mt) {
    const int m0 = mt * TILE;
    __syncthreads();  // prior selection reads done; also fences A-frag loads
    for (int i = t; i < 64 * 12; i += 256) {
      int r = i / 12, ch = i % 12;
      const uint4* sH = (const uint4*)(xh + ((size_t)b * NN + m0 + r) * CC);
      const uint4* sL = (const uint4*)(xl + ((size_t)b * NN + m0 + r) * CC);
      *(uint4*)&BsH[r * 104 + ch * 8] = sH[ch];
      *(uint4*)&BsL[r * 104 + ch * 8] = sL[ch];
    }
    if (t < TILE) sqm[t] = sq[b * NN + m0 + t];
    __syncthreads();

    #pragma unroll
    for (int tt = 0; tt < 4; ++tt) {
      const int brow = (tt * 16 + m16) * 104 + quad * 8;
      f32x4 acc = {0.f, 0.f, 0.f, 0.f};
      #pragma unroll
      for (int kc = 0; kc < 3; ++kc) {
        bf16x8 bh = *(const bf16x8*)&BsH[brow + kc * 32];
        bf16x8 bl = *(const bf16x8*)&BsL[brow + kc * 32];
        acc = __builtin_amdgcn_mfma_f32_16x16x32_bf16(ah[kc], bh, acc, 0, 0, 0);
        acc = __builtin_amdgcn_mfma_f32_16x16x32_bf16(ah[kc], bl, acc, 0, 0, 0);
        acc = __builtin_amdgcn_mfma_f32_16x16x32_bf16(al[kc], bh, acc, 0, 0, 0);
      }
      // C/D: col = lane&15, row = quad*4 + reg (within the 16x16 tile)
      const int crow = w * 16 + quad * 4;
      const int ccol = tt * 16 + m16;
      #pragma unroll
      for (int r = 0; r < 4; ++r) Cs[(crow + r) * 65 + ccol] = acc[r];
    }
    __syncthreads();

    float sr = srow[row];
    #pragma unroll
    for (int s2 = 0; s2 < 16; ++s2) {
      int mc = q * 16 + s2;
      float v = 2.f * Cs[row * 65 + mc] - sr - sqm[mc];
      topk_insert(v, m0 + mc, bv, bi, mnv, mni, mns);
    }
  }
  __syncthreads();

  // merge the 4 per-quarter lists of each row (scratch aliases A/Cs region)
  float* mvbuf = (float*)sA;                       // 2304 floats
  int* mibuf = (int*)(mvbuf + TILE * 4 * KNN);     // 2304 ints (total 18432 B)
  #pragma unroll
  for (int j = 0; j < KNN; ++j) {
    mvbuf[(row * 4 + q) * KNN + j] = bv[j];
    mibuf[(row * 4 + q) * KNN + j] = bi[j];
  }
  __syncthreads();
  if (t < TILE) {
    float fv[KNN]; int fi[KNN];
    #pragma unroll
    for (int j = 0; j < KNN; ++j) { fv[j] = NEG_BIG; fi[j] = 0x7fffffff; }
    float m2v = NEG_BIG; int m2i = 0x7fffffff; int m2s = 0;
    for (int qq = 0; qq < 4; ++qq)
      #pragma unroll
      for (int j = 0; j < KNN; ++j)
        topk_insert(mvbuf[(t * 4 + qq) * KNN + j], mibuf[(t * 4 + qq) * KNN + j],
                    fv, fi, m2v, m2i, m2s);
    size_t base = (((size_t)b * 4 + chunk) * NN + r0 + t) * KNN;
    #pragma unroll
    for (int j = 0; j < KNN; ++j) { cand_v[base + j] = fv[j]; cand_i[base + j] = fi[j]; }
  }
}

// ---------------------------------------------------------------------------
// K4: merge 4 chunk lists -> nn_idx (clamped to valid range).
// ---------------------------------------------------------------------------
__global__ __launch_bounds__(256) void k_nnmerge(const float* __restrict__ cand_v,
                                                 const int* __restrict__ cand_i,
                                                 int* __restrict__ nn_idx) {
  const int p = blockIdx.x * 256 + threadIdx.x;
  const int b = p / NN, n = p % NN;
  float fv[KNN]; int fi[KNN];
  #pragma unroll
  for (int j = 0; j < KNN; ++j) { fv[j] = NEG_BIG; fi[j] = 0x7fffffff; }
  float mnv = NEG_BIG; int mni = 0x7fffffff; int mns = 0;
  for (int ch = 0; ch < 4; ++ch) {
    size_t base = (((size_t)b * 4 + ch) * NN + n) * KNN;
    #pragma unroll
    for (int j = 0; j < KNN; ++j)
      topk_insert(cand_v[base + j], cand_i[base + j], fv, fi, mnv, mni, mns);
  }
  #pragma unroll
  for (int j = 0; j < KNN; ++j) {
    int v = fi[j];
    if ((unsigned)v >= (unsigned)NN) v = 0;  // sentinel guard: no wild gathers
    nn_idx[(size_t)p * KNN + j] = v;
  }
}

// ---------------------------------------------------------------------------
// K5: gather + grouped conv + bias + bn + relu + max over K.
// ---------------------------------------------------------------------------
__global__ __launch_bounds__(256) void k_gconv(const float* __restrict__ y1t,
                                               const int* __restrict__ nn_idx,
                                               const float* __restrict__ gw,
                                               const float* __restrict__ gb,
                                               const float* __restrict__ bng,
                                               float* __restrict__ ymax) {
  __shared__ float wl[C2 * 49];
  __shared__ float xi[PT * CC];
  __shared__ float fj[PT * CC * 12];
  __shared__ int idxl[PT * KNN];
  const int t = threadIdx.x;
  const int p0 = blockIdx.x * PT;
  const int b0 = p0 / NN;

  for (int i = t; i < C2 * 48; i += 256) wl[(i / 48) * 49 + (i % 48)] = gw[i];
  if (t < PT * KNN) {
    int v = nn_idx[(size_t)p0 * KNN + t];
    idxl[t] = ((unsigned)v < (unsigned)NN) ? v : 0;
  }
  for (int i = t; i < PT * CC; i += 256) xi[i] = y1t[(size_t)p0 * CC + i];
  __syncthreads();

  for (int i = t; i < PT * KNN * CC; i += 256) {
    int pk = i / CC, c = i % CC;
    int p = pk / KNN, k = pk % KNN;
    int j = idxl[p * KNN + k];
    float v = y1t[((size_t)b0 * NN + j) * CC + c] - xi[p * CC + c];
    fj[(p * CC + c) * 12 + k] = v;
  }
  __syncthreads();

  const int p = t >> 5, l = t & 31;
  const size_t pg = p0 + p;
  float* orow = ymax + pg * C2;
  const float* xip = xi + p * CC;
  const float* fp = fj + (size_t)p * CC * 12;

  auto bnrelu = [&](int oc, float a) -> float {
    float g = bng[oc], be = bng[C2 + oc], mn = bng[2 * C2 + oc], vr = bng[3 * C2 + oc];
    float inv = g / sqrtf(vr + 1e-5f);
    return fmaxf(fmaf(a + gb[oc], inv, be - mn * inv), 0.f);
  };

  {  // k-free half
    const int oc0 = l, oc1 = l + 32, oc2 = l + 64;
    const int cb0 = (oc0 / 48) * 48, cb1 = (oc1 / 48) * 48, cb2 = (oc2 / 48) * 48;
    float a0 = 0.f, a1 = 0.f, a2 = 0.f;
    #pragma unroll 8
    for (int c = 0; c < 48; ++c) {
      a0 = fmaf(wl[oc0 * 49 + c], xip[cb0 + c], a0);
      a1 = fmaf(wl[oc1 * 49 + c], xip[cb1 + c], a1);
      a2 = fmaf(wl[oc2 * 49 + c], xip[cb2 + c], a2);
    }
    orow[oc0] = bnrelu(oc0, a0);
    orow[oc1] = bnrelu(oc1, a1);
    orow[oc2] = bnrelu(oc2, a2);
  }
  {  // k-dependent half
    const int oc0 = 96 + l, oc1 = 128 + l, oc2 = 160 + l;
    const int db0 = ((oc0 - 96) / 48) * 48, db1 = ((oc1 - 96) / 48) * 48,
              db2 = ((oc2 - 96) / 48) * 48;
    float acc0[KNN], acc1[KNN], acc2[KNN];
    #pragma unroll
    for (int k = 0; k < KNN; ++k) { acc0[k] = 0.f; acc1[k] = 0.f; acc2[k] = 0.f; }
    #pragma unroll 2
    for (int c = 0; c < 48; ++c) {
      float w0 = wl[oc0 * 49 + c], w1 = wl[oc1 * 49 + c], w2 = wl[oc2 * 49 + c];
      const float* f0 = fp + (db0 + c) * 12;
      const float* f1 = fp + (db1 + c) * 12;
      const float* f2 = fp + (db2 + c) * 12;
      #pragma unroll
      for (int k = 0; k < KNN; ++k) {
        acc0[k] = fmaf(w0, f0[k], acc0[k]);
        acc1[k] = fmaf(w1, f1[k], acc1[k]);
        acc2[k] = fmaf(w2, f2[k], acc2[k]);
      }
    }
    {
      float g = bng[oc0], be = bng[C2 + oc0], mn = bng[2 * C2 + oc0], vr = bng[3 * C2 + oc0];
      float inv = g / sqrtf(vr + 1e-5f), sh = be - mn * inv, bs = gb[oc0], m = 0.f;
      #pragma unroll
      for (int k = 0; k < KNN; ++k) m = fmaxf(m, fmaxf(fmaf(acc0[k] + bs, inv, sh), 0.f));
      orow[oc0] = m;
    }
    {
      float g = bng[oc1], be = bng[C2 + oc1], mn = bng[2 * C2 + oc1], vr = bng[3 * C2 + oc1];
      float inv = g / sqrtf(vr + 1e-5f), sh = be - mn * inv, bs = gb[oc1], m = 0.f;
      #pragma unroll
      for (int k = 0; k < KNN; ++k) m = fmaxf(m, fmaxf(fmaf(acc1[k] + bs, inv, sh), 0.f));
      orow[oc1] = m;
    }
    {
      float g = bng[oc2], be = bng[C2 + oc2], mn = bng[2 * C2 + oc2], vr = bng[3 * C2 + oc2];
      float inv = g / sqrtf(vr + 1e-5f), sh = be - mn * inv, bs = gb[oc2], m = 0.f;
      #pragma unroll
      for (int k = 0; k < KNN; ++k) m = fmaxf(m, fmaxf(fmaf(acc2[k] + bs, inv, sh), 0.f));
      orow[oc2] = m;
    }
  }
}

// ---------------------------------------------------------------------------
// K6: out = bn2(fc2_w @ ymax + fc2_b) + x
// ---------------------------------------------------------------------------
__global__ __launch_bounds__(256) void k_fc2(const float* __restrict__ ymax,
                                             const float* __restrict__ w2,
                                             const float* __restrict__ b2,
                                             const float* __restrict__ bn2,
                                             const float* __restrict__ xin,
                                             float* __restrict__ out) {
  __shared__ float ys[64 * 193];
  const int b = blockIdx.y, n0 = blockIdx.x * 64, t = threadIdx.x;
  for (int i = t; i < 64 * C2; i += 256) {
    int nn = i / C2, c2 = i % C2;
    ys[nn * 193 + c2] = ymax[((size_t)b * NN + n0 + nn) * C2 + c2];
  }
  __syncthreads();
  const int nn = t & 63;
  const int og = __builtin_amdgcn_readfirstlane(t >> 6);
  float acc[24];
  #pragma unroll
  for (int i = 0; i < 24; ++i) acc[i] = 0.f;
  const float* yrow = ys + nn * 193;
  for (int c2 = 0; c2 < C2; ++c2) {
    float yv = yrow[c2];
    const float* wp = w2 + (size_t)(og * 24) * C2 + c2;
    #pragma unroll
    for (int oi = 0; oi < 24; ++oi) acc[oi] = fmaf(wp[oi * C2], yv, acc[oi]);
  }
  #pragma unroll
  for (int oi = 0; oi < 24; ++oi) {
    int o = og * 24 + oi;
    float g = bn2[o], be = bn2[CC + o], mn = bn2[2 * CC + o], vr = bn2[3 * CC + o];
    float inv = g / sqrtf(vr + 1e-5f);
    float v = fmaf(acc[oi] + b2[o], inv, be - mn * inv);
    size_t off = ((size_t)b * CC + o) * NN + n0 + nn;
    out[off] = v + xin[off];
  }
}

// ---------------------------------------------------------------------------
extern "C" void kernel_launch(void* const* d_in, const int* in_sizes, int n_in,
                              void* d_out, int out_size, void* d_ws, size_t ws_size,
                              hipStream_t stream) {
  const float* x     = (const float*)d_in[0];
  const float* fc1_w = (const float*)d_in[1];
  const float* fc1_b = (const float*)d_in[2];
  const float* bn1   = (const float*)d_in[3];
  const float* gc_w  = (const float*)d_in[4];
  const float* gc_b  = (const float*)d_in[5];
  const float* bng   = (const float*)d_in[6];
  const float* fc2_w = (const float*)d_in[7];
  const float* fc2_b = (const float*)d_in[8];
  const float* bn2   = (const float*)d_in[9];
  float* out = (float*)d_out;

  const size_t BNC = (size_t)BN_ * NN * CC;
  float* ws = (float*)d_ws;
  float* y1t = ws;                                   // B*N*C fp32
  unsigned short* xh = (unsigned short*)(y1t + BNC); // B*N*C bf16 hi
  unsigned short* xl = xh + BNC;                     // B*N*C bf16 lo
  float* sq     = ws + 2 * BNC;                      // B*N
  float* ymax   = sq + (size_t)BN_ * NN;             // B*N*C2
  float* cand_v = ymax + (size_t)BN_ * NN * C2;      // B*4*N*9
  int*   cand_i = (int*)(cand_v + (size_t)BN_ * 4 * NN * KNN);
  int*   nnidx  = (int*)(cand_i + (size_t)BN_ * 4 * NN * KNN);

  k_fc1<<<dim3(NN / 64, BN_), 256, 0, stream>>>(x, fc1_w, fc1_b, bn1, y1t);
  k_norm<<<dim3((BN_ * NN) / 256), 256, 0, stream>>>(y1t, xh, xl, sq);
  k_dist<<<dim3(NN / TILE, 4, BN_), 256, 0, stream>>>(xh, xl, sq, cand_v, cand_i);
  k_nnmerge<<<dim3((BN_ * NN) / 256), 256, 0, stream>>>(cand_v, cand_i, nnidx);
  k_gconv<<<dim3((BN_ * NN) / PT), 256, 0, stream>>>(y1t, nnidx, gc_w, gc_b, bng, ymax);
  k_fc2<<<dim3(NN / 64, BN_), 256, 0, stream>>>(ymax, fc2_w, fc2_b, bn2, x, out);
}

// Round 4
// 368.919 us; speedup vs baseline: 1.7436x; 1.4926x over previous
//
#include <hip/hip_runtime.h>
#include <cstdint>
#include <cstddef>

#define BN_   4
#define CC    96
#define C2    192
#define NN    3136
#define KNN   9
#define TILE  64
#define PT    8
#define NEG_BIG (-1.0e30f)

typedef __attribute__((ext_vector_type(8))) __bf16 bf16x8;
typedef __attribute__((ext_vector_type(4))) float f32x4;

__device__ __forceinline__ unsigned short f2bf(float f) {
  unsigned int u = __float_as_uint(f);
  unsigned int r = u + 0x7fffu + ((u >> 16) & 1u);   // RNE
  return (unsigned short)(r >> 16);
}
__device__ __forceinline__ float bf2f(unsigned short h) {
  return __uint_as_float(((unsigned int)h) << 16);
}
// monotone map: fmono(a) > fmono(b)  <=>  a > b  (as floats)
__device__ __forceinline__ unsigned int fmono(float f) {
  unsigned int s = __float_as_uint(f);
  return s ^ ((unsigned int)((int)s >> 31) | 0x80000000u);
}

// top-9 of u64 keys, unordered list + cached min slot.
// key = (fmono(v)<<32) | ~idx  => value desc, idx asc (jax top_k tie-break).
__device__ __forceinline__ void topk_u64(uint64_t key, uint64_t (&bk)[KNN],
                                         uint64_t& mnk, int& mns) {
  if (key > mnk) {
    #pragma unroll
    for (int j = 0; j < KNN; ++j) if (j == mns) bk[j] = key;
    mnk = bk[0]; mns = 0;
    #pragma unroll
    for (int j = 1; j < KNN; ++j) if (bk[j] < mnk) { mnk = bk[j]; mns = j; }
  }
}

// ---------------------------------------------------------------------------
// K1: y1t[b][n][o] = bn1(fc1_w @ x + fc1_b).  n-major output for gathers.
// ---------------------------------------------------------------------------
__global__ __launch_bounds__(256) void k_fc1(const float* __restrict__ x,
                                             const float* __restrict__ w,
                                             const float* __restrict__ bias,
                                             const float* __restrict__ bn,
                                             float* __restrict__ y1t) {
  __shared__ float xs[CC * 64];  // [c][64]
  const int b = blockIdx.y, n0 = blockIdx.x * 64;
  const int t = threadIdx.x;
  for (int i = t; i < CC * 64; i += 256) {
    int c = i >> 6, nn = i & 63;
    xs[i] = x[((size_t)b * CC + c) * NN + n0 + nn];
  }
  __syncthreads();
  const int nn = t & 63;
  const int og = __builtin_amdgcn_readfirstlane(t >> 6);
  float acc[24];
  #pragma unroll
  for (int i = 0; i < 24; ++i) acc[i] = 0.f;
  for (int c = 0; c < CC; ++c) {
    float xv = xs[c * 64 + nn];
    const float* wp = w + (size_t)(og * 24) * CC + c;
    #pragma unroll
    for (int oi = 0; oi < 24; ++oi) acc[oi] = fmaf(wp[oi * CC], xv, acc[oi]);
  }
  #pragma unroll
  for (int oi = 0; oi < 24; ++oi) {
    int o = og * 24 + oi;
    float g = bn[o], be = bn[CC + o], mn = bn[2 * CC + o], vr = bn[3 * CC + o];
    float inv = g / sqrtf(vr + 1e-5f);
    float v = fmaf(acc[oi] + bias[o], inv, be - mn * inv);
    y1t[((size_t)b * NN + n0 + nn) * CC + o] = v;
  }
}

// ---------------------------------------------------------------------------
// K2: per-position L2 norm; emit bf16 split (hi, lo) of xn + sq.
// ---------------------------------------------------------------------------
__global__ __launch_bounds__(256) void k_norm(const float* __restrict__ y1t,
                                              unsigned short* __restrict__ xh,
                                              unsigned short* __restrict__ xl,
                                              float* __restrict__ sq) {
  const int p = blockIdx.x * 256 + threadIdx.x;  // 49*256 == 12544 exactly
  const float* row = y1t + (size_t)p * CC;
  float s = 0.f;
  for (int c = 0; c < CC; c += 4) {
    float4 v = *(const float4*)(row + c);
    s += v.x * v.x; s += v.y * v.y; s += v.z * v.z; s += v.w * v.w;
  }
  float inv = 1.f / fmaxf(sqrtf(s), 1e-12f);
  float sqs = 0.f;
  unsigned short* hrow = xh + (size_t)p * CC;
  unsigned short* lrow = xl + (size_t)p * CC;
  for (int c = 0; c < CC; ++c) {
    float v = row[c] * inv;
    sqs += v * v;
    unsigned short h = f2bf(v);
    float lo = v - bf2f(h);
    hrow[c] = h;
    lrow[c] = f2bf(lo);
  }
  sq[p] = sqs;
}

// ---------------------------------------------------------------------------
// K3: Gram via bf16-split MFMA with SWAPPED operands: mfma(bfrag, afrag)
// puts D-col = our Gram row, so each lane's accumulators all belong to ONE
// row (gr) and selection runs in registers.  No Cs, no A-staging LDS, one
// barrier pair per column tile.
// ---------------------------------------------------------------------------
__global__ __launch_bounds__(256) void k_dist(const unsigned short* __restrict__ xh,
                                              const unsigned short* __restrict__ xl,
                                              const float* __restrict__ sq,
                                              uint64_t* __restrict__ cand_k) {
  __shared__ __align__(16) unsigned short sB[2 * 64 * 104];  // 26624 B
  __shared__ __align__(16) float sqm[TILE];
  unsigned short* BsH = sB;
  unsigned short* BsL = sB + 64 * 104;

  const int rt = blockIdx.x, chunk = blockIdx.y, b = blockIdx.z;
  const int r0 = rt * TILE;
  const int t = threadIdx.x;
  const int lane = t & 63, w = t >> 6;
  const int m16 = lane & 15, quad = lane >> 4;
  const int mt0 = (49 * chunk) / 4, mt1 = (49 * (chunk + 1)) / 4;

  // This lane's Gram row; A-fragments straight from global (once per block).
  const int gr = r0 + w * 16 + m16;
  bf16x8 ah[3], al[3];
  {
    const unsigned short* pH = xh + ((size_t)b * NN + gr) * CC + quad * 8;
    const unsigned short* pL = xl + ((size_t)b * NN + gr) * CC + quad * 8;
    #pragma unroll
    for (int kc = 0; kc < 3; ++kc) {
      ah[kc] = *(const bf16x8*)(pH + kc * 32);
      al[kc] = *(const bf16x8*)(pL + kc * 32);
    }
  }
  const float sr = sq[b * NN + gr];

  uint64_t bk[KNN];
  #pragma unroll
  for (int j = 0; j < KNN; ++j) bk[j] = 0ull;
  uint64_t mnk = 0ull; int mns = 0;

  for (int mt = mt0; mt < mt1; ++mt) {
    const int m0 = mt * TILE;
    __syncthreads();  // prior tile's B-frag reads done before overwrite
    for (int i = t; i < 64 * 12; i += 256) {
      int r = i / 12, ch = i % 12;
      const uint4* sH = (const uint4*)(xh + ((size_t)b * NN + m0 + r) * CC);
      const uint4* sL = (const uint4*)(xl + ((size_t)b * NN + m0 + r) * CC);
      *(uint4*)&BsH[r * 104 + ch * 8] = sH[ch];
      *(uint4*)&BsL[r * 104 + ch * 8] = sL[ch];
    }
    if (t < TILE) sqm[t] = sq[b * NN + m0 + t];
    __syncthreads();

    #pragma unroll
    for (int tt = 0; tt < 4; ++tt) {
      const int brow = (tt * 16 + m16) * 104 + quad * 8;
      f32x4 acc = {0.f, 0.f, 0.f, 0.f};
      #pragma unroll
      for (int kc = 0; kc < 3; ++kc) {
        bf16x8 bh = *(const bf16x8*)&BsH[brow + kc * 32];
        bf16x8 bl = *(const bf16x8*)&BsL[brow + kc * 32];
        acc = __builtin_amdgcn_mfma_f32_16x16x32_bf16(bh, ah[kc], acc, 0, 0, 0);
        acc = __builtin_amdgcn_mfma_f32_16x16x32_bf16(bl, ah[kc], acc, 0, 0, 0);
        acc = __builtin_amdgcn_mfma_f32_16x16x32_bf16(bh, al[kc], acc, 0, 0, 0);
      }
      // lane's candidates: cols m0 + tt*16 + quad*4 + r, all for row gr
      float4 s4 = *(const float4*)&sqm[tt * 16 + quad * 4];  // broadcast read
      const float sv[4] = {s4.x, s4.y, s4.z, s4.w};
      #pragma unroll
      for (int r = 0; r < 4; ++r) {
        float v = 2.f * acc[r] - sr - sv[r];
        int col = m0 + tt * 16 + quad * 4 + r;
        uint64_t key = ((uint64_t)fmono(v) << 32) | (unsigned int)~col;
        topk_u64(key, bk, mnk, mns);
      }
    }
  }
  __syncthreads();

  // merge the 4 per-quad lists of each row (scratch aliases sB)
  uint64_t* sk = (uint64_t*)sB;   // 64 rows * 4 quads * 9 * 8B = 18432 B
  #pragma unroll
  for (int j = 0; j < KNN; ++j) sk[((w * 16 + m16) * 4 + quad) * KNN + j] = bk[j];
  __syncthreads();
  if (t < TILE) {
    uint64_t fk[KNN];
    #pragma unroll
    for (int j = 0; j < KNN; ++j) fk[j] = 0ull;
    uint64_t m2 = 0ull; int m2s = 0;
    for (int qq = 0; qq < 4; ++qq)
      #pragma unroll
      for (int j = 0; j < KNN; ++j)
        topk_u64(sk[(t * 4 + qq) * KNN + j], fk, m2, m2s);
    size_t base = (((size_t)b * 4 + chunk) * NN + r0 + t) * KNN;
    #pragma unroll
    for (int j = 0; j < KNN; ++j) cand_k[base + j] = fk[j];
  }
}

// ---------------------------------------------------------------------------
// K4: merge 4 chunk lists -> nn_idx (clamped to valid range).
// ---------------------------------------------------------------------------
__global__ __launch_bounds__(256) void k_nnmerge(const uint64_t* __restrict__ cand_k,
                                                 int* __restrict__ nn_idx) {
  const int p = blockIdx.x * 256 + threadIdx.x;
  const int b = p / NN, n = p % NN;
  uint64_t fk[KNN];
  #pragma unroll
  for (int j = 0; j < KNN; ++j) fk[j] = 0ull;
  uint64_t mnk = 0ull; int mns = 0;
  for (int ch = 0; ch < 4; ++ch) {
    size_t base = (((size_t)b * 4 + ch) * NN + n) * KNN;
    #pragma unroll
    for (int j = 0; j < KNN; ++j) topk_u64(cand_k[base + j], fk, mnk, mns);
  }
  #pragma unroll
  for (int j = 0; j < KNN; ++j) {
    int v = (int)(~(unsigned int)fk[j]);
    if ((unsigned)v >= (unsigned)NN) v = 0;  // sentinel guard: no wild gathers
    nn_idx[(size_t)p * KNN + j] = v;
  }
}

// ---------------------------------------------------------------------------
// K5: gather + grouped conv + bias + bn + relu + max over K.
// ---------------------------------------------------------------------------
__global__ __launch_bounds__(256) void k_gconv(const float* __restrict__ y1t,
                                               const int* __restrict__ nn_idx,
                                               const float* __restrict__ gw,
                                               const float* __restrict__ gb,
                                               const float* __restrict__ bng,
                                               float* __restrict__ ymax) {
  __shared__ float wl[C2 * 49];
  __shared__ float xi[PT * CC];
  __shared__ float fj[PT * CC * 12];
  __shared__ int idxl[PT * KNN];
  const int t = threadIdx.x;
  const int p0 = blockIdx.x * PT;
  const int b0 = p0 / NN;

  for (int i = t; i < C2 * 48; i += 256) wl[(i / 48) * 49 + (i % 48)] = gw[i];
  if (t < PT * KNN) {
    int v = nn_idx[(size_t)p0 * KNN + t];
    idxl[t] = ((unsigned)v < (unsigned)NN) ? v : 0;
  }
  for (int i = t; i < PT * CC; i += 256) xi[i] = y1t[(size_t)p0 * CC + i];
  __syncthreads();

  for (int i = t; i < PT * KNN * CC; i += 256) {
    int pk = i / CC, c = i % CC;
    int p = pk / KNN, k = pk % KNN;
    int j = idxl[p * KNN + k];
    float v = y1t[((size_t)b0 * NN + j) * CC + c] - xi[p * CC + c];
    fj[(p * CC + c) * 12 + k] = v;
  }
  __syncthreads();

  const int p = t >> 5, l = t & 31;
  const size_t pg = p0 + p;
  float* orow = ymax + pg * C2;
  const float* xip = xi + p * CC;
  const float* fp = fj + (size_t)p * CC * 12;

  auto bnrelu = [&](int oc, float a) -> float {
    float g = bng[oc], be = bng[C2 + oc], mn = bng[2 * C2 + oc], vr = bng[3 * C2 + oc];
    float inv = g / sqrtf(vr + 1e-5f);
    return fmaxf(fmaf(a + gb[oc], inv, be - mn * inv), 0.f);
  };

  {  // k-free half
    const int oc0 = l, oc1 = l + 32, oc2 = l + 64;
    const int cb0 = (oc0 / 48) * 48, cb1 = (oc1 / 48) * 48, cb2 = (oc2 / 48) * 48;
    float a0 = 0.f, a1 = 0.f, a2 = 0.f;
    #pragma unroll 8
    for (int c = 0; c < 48; ++c) {
      a0 = fmaf(wl[oc0 * 49 + c], xip[cb0 + c], a0);
      a1 = fmaf(wl[oc1 * 49 + c], xip[cb1 + c], a1);
      a2 = fmaf(wl[oc2 * 49 + c], xip[cb2 + c], a2);
    }
    orow[oc0] = bnrelu(oc0, a0);
    orow[oc1] = bnrelu(oc1, a1);
    orow[oc2] = bnrelu(oc2, a2);
  }
  {  // k-dependent half
    const int oc0 = 96 + l, oc1 = 128 + l, oc2 = 160 + l;
    const int db0 = ((oc0 - 96) / 48) * 48, db1 = ((oc1 - 96) / 48) * 48,
              db2 = ((oc2 - 96) / 48) * 48;
    float acc0[KNN], acc1[KNN], acc2[KNN];
    #pragma unroll
    for (int k = 0; k < KNN; ++k) { acc0[k] = 0.f; acc1[k] = 0.f; acc2[k] = 0.f; }
    #pragma unroll 2
    for (int c = 0; c < 48; ++c) {
      float w0 = wl[oc0 * 49 + c], w1 = wl[oc1 * 49 + c], w2 = wl[oc2 * 49 + c];
      const float* f0 = fp + (db0 + c) * 12;
      const float* f1 = fp + (db1 + c) * 12;
      const float* f2 = fp + (db2 + c) * 12;
      #pragma unroll
      for (int k = 0; k < KNN; ++k) {
        acc0[k] = fmaf(w0, f0[k], acc0[k]);
        acc1[k] = fmaf(w1, f1[k], acc1[k]);
        acc2[k] = fmaf(w2, f2[k], acc2[k]);
      }
    }
    {
      float g = bng[oc0], be = bng[C2 + oc0], mn = bng[2 * C2 + oc0], vr = bng[3 * C2 + oc0];
      float inv = g / sqrtf(vr + 1e-5f), sh = be - mn * inv, bs = gb[oc0], m = 0.f;
      #pragma unroll
      for (int k = 0; k < KNN; ++k) m = fmaxf(m, fmaxf(fmaf(acc0[k] + bs, inv, sh), 0.f));
      orow[oc0] = m;
    }
    {
      float g = bng[oc1], be = bng[C2 + oc1], mn = bng[2 * C2 + oc1], vr = bng[3 * C2 + oc1];
      float inv = g / sqrtf(vr + 1e-5f), sh = be - mn * inv, bs = gb[oc1], m = 0.f;
      #pragma unroll
      for (int k = 0; k < KNN; ++k) m = fmaxf(m, fmaxf(fmaf(acc1[k] + bs, inv, sh), 0.f));
      orow[oc1] = m;
    }
    {
      float g = bng[oc2], be = bng[C2 + oc2], mn = bng[2 * C2 + oc2], vr = bng[3 * C2 + oc2];
      float inv = g / sqrtf(vr + 1e-5f), sh = be - mn * inv, bs = gb[oc2], m = 0.f;
      #pragma unroll
      for (int k = 0; k < KNN; ++k) m = fmaxf(m, fmaxf(fmaf(acc2[k] + bs, inv, sh), 0.f));
      orow[oc2] = m;
    }
  }
}

// ---------------------------------------------------------------------------
// K6: out = bn2(fc2_w @ ymax + fc2_b) + x
// ---------------------------------------------------------------------------
__global__ __launch_bounds__(256) void k_fc2(const float* __restrict__ ymax,
                                             const float* __restrict__ w2,
                                             const float* __restrict__ b2,
                                             const float* __restrict__ bn2,
                                             const float* __restrict__ xin,
                                             float* __restrict__ out) {
  __shared__ float ys[64 * 193];
  const int b = blockIdx.y, n0 = blockIdx.x * 64, t = threadIdx.x;
  for (int i = t; i < 64 * C2; i += 256) {
    int nn = i / C2, c2 = i % C2;
    ys[nn * 193 + c2] = ymax[((size_t)b * NN + n0 + nn) * C2 + c2];
  }
  __syncthreads();
  const int nn = t & 63;
  const int og = __builtin_amdgcn_readfirstlane(t >> 6);
  float acc[24];
  #pragma unroll
  for (int i = 0; i < 24; ++i) acc[i] = 0.f;
  const float* yrow = ys + nn * 193;
  for (int c2 = 0; c2 < C2; ++c2) {
    float yv = yrow[c2];
    const float* wp = w2 + (size_t)(og * 24) * C2 + c2;
    #pragma unroll
    for (int oi = 0; oi < 24; ++oi) acc[oi] = fmaf(wp[oi * C2], yv, acc[oi]);
  }
  #pragma unroll
  for (int oi = 0; oi < 24; ++oi) {
    int o = og * 24 + oi;
    float g = bn2[o], be = bn2[CC + o], mn = bn2[2 * CC + o], vr = bn2[3 * CC + o];
    float inv = g / sqrtf(vr + 1e-5f);
    float v = fmaf(acc[oi] + b2[o], inv, be - mn * inv);
    size_t off = ((size_t)b * CC + o) * NN + n0 + nn;
    out[off] = v + xin[off];
  }
}

// ---------------------------------------------------------------------------
extern "C" void kernel_launch(void* const* d_in, const int* in_sizes, int n_in,
                              void* d_out, int out_size, void* d_ws, size_t ws_size,
                              hipStream_t stream) {
  const float* x     = (const float*)d_in[0];
  const float* fc1_w = (const float*)d_in[1];
  const float* fc1_b = (const float*)d_in[2];
  const float* bn1   = (const float*)d_in[3];
  const float* gc_w  = (const float*)d_in[4];
  const float* gc_b  = (const float*)d_in[5];
  const float* bng   = (const float*)d_in[6];
  const float* fc2_w = (const float*)d_in[7];
  const float* fc2_b = (const float*)d_in[8];
  const float* bn2   = (const float*)d_in[9];
  float* out = (float*)d_out;

  const size_t BNC = (size_t)BN_ * NN * CC;
  float* ws = (float*)d_ws;
  float* y1t = ws;                                   // B*N*C fp32
  unsigned short* xh = (unsigned short*)(y1t + BNC); // B*N*C bf16 hi
  unsigned short* xl = xh + BNC;                     // B*N*C bf16 lo
  float* sq     = ws + 2 * BNC;                      // B*N
  float* ymax   = sq + (size_t)BN_ * NN;             // B*N*C2
  uint64_t* cand_k = (uint64_t*)(ymax + (size_t)BN_ * NN * C2);  // B*4*N*9 u64
  int* nnidx = (int*)(cand_k + (size_t)BN_ * 4 * NN * KNN);

  k_fc1<<<dim3(NN / 64, BN_), 256, 0, stream>>>(x, fc1_w, fc1_b, bn1, y1t);
  k_norm<<<dim3((BN_ * NN) / 256), 256, 0, stream>>>(y1t, xh, xl, sq);
  k_dist<<<dim3(NN / TILE, 4, BN_), 256, 0, stream>>>(xh, xl, sq, cand_k);
  k_nnmerge<<<dim3((BN_ * NN) / 256), 256, 0, stream>>>(cand_k, nnidx);
  k_gconv<<<dim3((BN_ * NN) / PT), 256, 0, stream>>>(y1t, nnidx, gc_w, gc_b, bng, ymax);
  k_fc2<<<dim3(NN / 64, BN_), 256, 0, stream>>>(ymax, fc2_w, fc2_b, bn2, x, out);
}